// Round 4
// baseline (999.022 us; speedup 1.0000x reference)
//
#include <hip/hip_runtime.h>
#include <math.h>

// GAT: 3 hidden GATConv layers (H=4, D=64, HID=256) + LN + leaky + residual,
// then output GATConv (H=1, C=40). N=100000 nodes, E=1600000 edges.
//
// Round 13: (1) alloc_kernel (100K value-returning atomicAdds on ONE address,
// lane-serialized) replaced by a 3-pass exclusive scan (block LDS scan ->
// 98-entry block-sum scan -> add base). (2) aggregate_hidden split into two
// half-range dispatches per layer: zero perf cost, halves the top-5
// visibility floor so the true cost of hist/scatter/aggregate_out/gemm
// shows up in next round's counters. GEMMs unchanged (R11/R12 proved them
// fast - three different structures, same total).

#define NEG_SLOPE 0.2f

typedef __attribute__((ext_vector_type(8))) short bf16x8;
typedef __attribute__((ext_vector_type(4))) float floatx4;

__device__ __forceinline__ float leaky(float x) { return x >= 0.f ? x : NEG_SLOPE * x; }

__device__ __forceinline__ unsigned short f2bf(float f) {
    unsigned u = __builtin_bit_cast(unsigned, f);
    u += 0x7fffu + ((u >> 16) & 1u);  // RNE
    return (unsigned short)(u >> 16);
}
__device__ __forceinline__ float bf2f(unsigned short h) {
    unsigned u = ((unsigned)h) << 16;
    return __builtin_bit_cast(float, u);
}

// ---------------- CSR build ----------------
__global__ void zero_i32(int* __restrict__ p, int n) {
    int i = blockIdx.x * blockDim.x + threadIdx.x;
    if (i < n) p[i] = 0;
}

__global__ void hist_kernel(const int* __restrict__ dst, int* __restrict__ counts, int E) {
    int e = blockIdx.x * blockDim.x + threadIdx.x;
    if (e < E) atomicAdd(&counts[dst[e]], 1);
}

// exclusive scan pass 1: per-block (1024 elems) local scan + block sum
__global__ __launch_bounds__(256) void scan1(const int* __restrict__ counts,
                                             int* __restrict__ local,
                                             int* __restrict__ bsum, int N) {
    __shared__ int s[256];
    const int t = threadIdx.x;
    const int base = blockIdx.x * 1024 + t * 4;
    int c0 = 0, c1 = 0, c2 = 0, c3 = 0;
    if (base + 3 < N) {
        int4 v = *(const int4*)(counts + base);
        c0 = v.x; c1 = v.y; c2 = v.z; c3 = v.w;
    } else {
        if (base + 0 < N) c0 = counts[base + 0];
        if (base + 1 < N) c1 = counts[base + 1];
        if (base + 2 < N) c2 = counts[base + 2];
    }
    int tsum = c0 + c1 + c2 + c3;
    s[t] = tsum;
    __syncthreads();
    for (int off = 1; off < 256; off <<= 1) {
        int v = (t >= off) ? s[t - off] : 0;
        __syncthreads();
        s[t] += v;
        __syncthreads();
    }
    int excl = s[t] - tsum;
    if (t == 255) bsum[blockIdx.x] = s[255];
    if (base + 0 < N) local[base + 0] = excl;
    if (base + 1 < N) local[base + 1] = excl + c0;
    if (base + 2 < N) local[base + 2] = excl + c0 + c1;
    if (base + 3 < N) local[base + 3] = excl + c0 + c1 + c2;
}

// pass 2: exclusive scan of block sums (nb <= 128), single block
__global__ void scan2(int* __restrict__ bsum, int nb) {
    __shared__ int s[128];
    const int t = threadIdx.x;
    int v = (t < nb) ? bsum[t] : 0;
    s[t] = v;
    __syncthreads();
    for (int off = 1; off < 128; off <<= 1) {
        int u = (t >= off) ? s[t - off] : 0;
        __syncthreads();
        s[t] += u;
        __syncthreads();
    }
    if (t < nb) bsum[t] = s[t] - v;
}

// pass 3: add block base; init start + cursor
__global__ __launch_bounds__(256) void scan3(const int* __restrict__ local,
                                             const int* __restrict__ bsum,
                                             int* __restrict__ start,
                                             int* __restrict__ cursor, int N) {
    int i = blockIdx.x * 256 + threadIdx.x;
    if (i < N) {
        int v = local[i] + bsum[i >> 10];
        start[i] = v;
        cursor[i] = v;
    }
}

__global__ void scatter_kernel(const int* __restrict__ src, const int* __restrict__ dst,
                               int* __restrict__ cursor, int* __restrict__ col, int E) {
    int e = blockIdx.x * blockDim.x + threadIdx.x;
    if (e < E) {
        int p = atomicAdd(&cursor[dst[e]], 1);
        col[p] = src[e];
    }
}

// ---------------- fp32 -> bf16 bulk convert ----------------
__global__ void convert_bf(const float* __restrict__ src, unsigned short* __restrict__ dst,
                           int n4) {
    int i = blockIdx.x * blockDim.x + threadIdx.x;
    if (i < n4) {
        float4 v = *(const float4*)(src + (size_t)i * 4);
        ushort4 s;
        s.x = f2bf(v.x); s.y = f2bf(v.y); s.z = f2bf(v.z); s.w = f2bf(v.w);
        *(ushort4*)(dst + (size_t)i * 4) = s;
    }
}

// ---------------- weight pre-transpose: Wt[l][n][k] = bf16(W[l][k][n]) ----------------
__global__ void transpose_w(const float* __restrict__ W, unsigned short* __restrict__ Wt) {
    int idx = blockIdx.x * 256 + threadIdx.x;
    int l = idx >> 16, r = idx & 65535;
    int k = r >> 8, n = r & 255;
    Wt[l * 65536 + n * 256 + k] = f2bf(W[l * 65536 + k * 256 + n]);
}

__global__ void transpose_wo(const float* __restrict__ W, unsigned short* __restrict__ Wt) {
    int idx = blockIdx.x * 256 + threadIdx.x;
    int n = idx >> 8, k = idx & 255;
    Wt[n * 256 + k] = (n < 40) ? f2bf(W[k * 40 + n]) : (unsigned short)0;
}

// ---------------- weight-resident persistent MFMA GEMM + fused scores ----------------
#define BPAD 264
#define ALD 40
__global__ __launch_bounds__(512, 2) void gemm_bf16_fused(
    const unsigned short* __restrict__ A, const unsigned short* __restrict__ Wt,
    const float* __restrict__ al, const float* __restrict__ ar,
    unsigned short* __restrict__ Cb, float* __restrict__ el, float* __restrict__ er, int M) {
    __shared__ unsigned short Bs[256 * BPAD];   // 132 KB
    __shared__ unsigned short As[2][128 * ALD]; // 20.5 KB
    const int tid = threadIdx.x;
    const int lane = tid & 63, wid = tid >> 6;
    const int wm = (wid >> 2) * 64;   // 0 or 64
    const int wn = (wid & 3) * 64;    // 0,64,128,192
    const int q = lane >> 4, m = lane & 15;

#pragma unroll
    for (int i = 0; i < 16; ++i) {
        int flat = tid + 512 * i;            // 16B units
        int row = flat >> 5, col8 = (flat & 31) * 8;
        *(bf16x8*)&Bs[row * BPAD + col8] = *(const bf16x8*)(Wt + row * 256 + col8);
    }
    __syncthreads();

    const int rA = tid >> 2, k8 = (tid & 3) * 8;
    const int head = wid & 3;
    const float* alh = al + head * 64;
    const float* arh = ar + head * 64;
    const int c = lane & 15;
    float a0 = alh[c], a1 = alh[16 + c], a2 = alh[32 + c], a3 = alh[48 + c];
    float r0 = arh[c], r1 = arh[16 + c], r2 = arh[32 + c], r3 = arh[48 + c];

    const int ntiles = (M + 127) >> 7;
    for (int t = blockIdx.x; t < ntiles; t += gridDim.x) {
        const int row0 = t << 7;
        int agr = row0 + rA; if (agr >= M) agr = M - 1;
        const unsigned short* arow = A + (size_t)agr * 256 + k8;
        bf16x8 pa = *(const bf16x8*)arow;

        floatx4 acc[4][4] = {};
        int cur = 0;
        for (int kb = 0; kb < 256; kb += 32) {
            *(bf16x8*)&As[cur][rA * ALD + k8] = pa;
            __syncthreads();
            if (kb + 32 < 256) pa = *(const bf16x8*)(arow + kb + 32);
            bf16x8 af[4], bfr[4];
#pragma unroll
            for (int i = 0; i < 4; ++i) {
                af[i] = *(const bf16x8*)&As[cur][(wm + i * 16 + m) * ALD + q * 8];
                bfr[i] = *(const bf16x8*)&Bs[(wn + i * 16 + m) * BPAD + kb + q * 8];
            }
#pragma unroll
            for (int i = 0; i < 4; ++i)
#pragma unroll
                for (int j = 0; j < 4; ++j)
                    acc[i][j] = __builtin_amdgcn_mfma_f32_16x16x32_bf16(af[i], bfr[j], acc[i][j], 0, 0, 0);
            cur ^= 1;
        }

#pragma unroll
        for (int i = 0; i < 4; ++i)
#pragma unroll
            for (int j = 0; j < 4; ++j)
#pragma unroll
                for (int r = 0; r < 4; ++r) {
                    int grow = row0 + wm + i * 16 + q * 4 + r;
                    int gcol = wn + j * 16 + c;
                    if (grow < M) Cb[(size_t)grow * 256 + gcol] = f2bf(acc[i][j][r]);
                }

#pragma unroll
        for (int i = 0; i < 4; ++i)
#pragma unroll
            for (int r = 0; r < 4; ++r) {
                float pel = acc[i][0][r] * a0 + acc[i][1][r] * a1 + acc[i][2][r] * a2 + acc[i][3][r] * a3;
                float per = acc[i][0][r] * r0 + acc[i][1][r] * r1 + acc[i][2][r] * r2 + acc[i][3][r] * r3;
#pragma unroll
                for (int off = 8; off >= 1; off >>= 1) {
                    pel += __shfl_xor(pel, off);
                    per += __shfl_xor(per, off);
                }
                if (c == 0) {
                    int grow = row0 + wm + i * 16 + q * 4 + r;
                    if (grow < M) {
                        el[(size_t)grow * 4 + head] = pel;
                        er[(size_t)grow * 4 + head] = per;
                    }
                }
            }
        __syncthreads();
    }
}

// ---------------- output MFMA GEMM: feat_o[N,40] bf16 = h_bf[N,256] @ W_o ----------------
#define LDSK 40
#define BSTRIDE 264
__global__ __launch_bounds__(256) void gemm_out_mfma(const unsigned short* __restrict__ h,
                                                     const unsigned short* __restrict__ Wt,
                                                     const float* __restrict__ alo,
                                                     const float* __restrict__ aro,
                                                     unsigned short* __restrict__ feat_o,
                                                     float* __restrict__ elo,
                                                     float* __restrict__ ero, int N) {
    __shared__ unsigned short As[128 * LDSK];
    __shared__ unsigned short Bs[48 * BSTRIDE];
    const int tid = threadIdx.x;
    const int row0 = blockIdx.x * 128;
    const int lane = tid & 63, wid = tid >> 6;

#pragma unroll
    for (int i = 0; i < 6; ++i) {
        int f = tid + 256 * i;
        int n = f >> 5, kk = (f & 31) * 8;
        *(bf16x8*)&Bs[n * BSTRIDE + kk] = *(const bf16x8*)(Wt + n * 256 + kk);
    }
    __syncthreads();

    floatx4 acc[2][3] = {};
    for (int kb = 0; kb < 256; kb += 32) {
#pragma unroll
        for (int i = 0; i < 2; ++i) {
            int idx = tid + 256 * i;
            int r = idx >> 2, k8 = (idx & 3) * 8;
            int gr = row0 + r;
            bf16x8 v = {};
            if (gr < N) v = *(const bf16x8*)(h + (size_t)gr * 256 + kb + k8);
            *(bf16x8*)&As[r * LDSK + k8] = v;
        }
        __syncthreads();
        const int q = lane >> 4, m = lane & 15;
        bf16x8 af[2], bfr[3];
#pragma unroll
        for (int i = 0; i < 2; ++i)
            af[i] = *(const bf16x8*)&As[(wid * 32 + i * 16 + m) * LDSK + q * 8];
#pragma unroll
        for (int j = 0; j < 3; ++j)
            bfr[j] = *(const bf16x8*)&Bs[(j * 16 + m) * BSTRIDE + kb + q * 8];
#pragma unroll
        for (int i = 0; i < 2; ++i)
#pragma unroll
            for (int j = 0; j < 3; ++j)
                acc[i][j] = __builtin_amdgcn_mfma_f32_16x16x32_bf16(af[i], bfr[j], acc[i][j], 0, 0, 0);
        __syncthreads();
    }

    const int q = lane >> 4, c = lane & 15;
#pragma unroll
    for (int i = 0; i < 2; ++i)
#pragma unroll
        for (int j = 0; j < 3; ++j)
#pragma unroll
            for (int r = 0; r < 4; ++r) {
                int grow = row0 + wid * 32 + i * 16 + q * 4 + r;
                int gcol = j * 16 + c;
                if (grow < N && gcol < 40) feat_o[(size_t)grow * 40 + gcol] = f2bf(acc[i][j][r]);
            }

    float aj[3], rj[3];
#pragma unroll
    for (int j = 0; j < 3; ++j) {
        int gcol = j * 16 + c;
        aj[j] = gcol < 40 ? alo[gcol] : 0.f;
        rj[j] = gcol < 40 ? aro[gcol] : 0.f;
    }
#pragma unroll
    for (int i = 0; i < 2; ++i)
#pragma unroll
        for (int r = 0; r < 4; ++r) {
            float pl = acc[i][0][r] * aj[0] + acc[i][1][r] * aj[1] + acc[i][2][r] * aj[2];
            float pr = acc[i][0][r] * rj[0] + acc[i][1][r] * rj[1] + acc[i][2][r] * rj[2];
#pragma unroll
            for (int off = 8; off >= 1; off >>= 1) {
                pl += __shfl_xor(pl, off);
                pr += __shfl_xor(pr, off);
            }
            if (c == 0) {
                int grow = row0 + wid * 32 + i * 16 + q * 4 + r;
                if (grow < N) {
                    elo[grow] = pl;
                    ero[grow] = pr;
                }
            }
        }
}

// ---------------- hidden-layer aggregation: single pass + fused epilogue ----------------
// node range [node0, nend) so the launcher can split it into halves.
__global__ __launch_bounds__(256) void aggregate_hidden(
    const unsigned short* __restrict__ feat, const float* __restrict__ el,
    const float* __restrict__ er, const int* __restrict__ start, const int* __restrict__ endp,
    const int* __restrict__ col, const float* __restrict__ bias, const float* __restrict__ lng,
    const float* __restrict__ lnb, const unsigned short* __restrict__ h_in,
    unsigned short* __restrict__ h_out, int node0, int nend) {
    int node = node0 + blockIdx.x * 4 + (threadIdx.x >> 6);
    int lane = threadIdx.x & 63;
    if (node >= nend) return;
    int begin = __builtin_amdgcn_readfirstlane(start[node]);
    int end = __builtin_amdgcn_readfirstlane(endp[node]);
    const int head = lane >> 4;
    const float erh = er[(size_t)node * 4 + head];

    const int ch = lane * 4;
    const unsigned short* fbase = feat + ch;
    const size_t hstr = 256;
    float4 acc = {0.f, 0.f, 0.f, 0.f};
    float ssum = 0.f;
    int e = begin;
    for (; e + 7 < end; e += 8) {
        int sA = col[e], sB = col[e + 1], sC = col[e + 2], sD = col[e + 3];
        int sE = col[e + 4], sF = col[e + 5], sG = col[e + 6], sH = col[e + 7];
        float eA = el[(size_t)sA * 4 + head];
        float eB = el[(size_t)sB * 4 + head];
        float eC = el[(size_t)sC * 4 + head];
        float eD = el[(size_t)sD * 4 + head];
        float eE = el[(size_t)sE * 4 + head];
        float eF = el[(size_t)sF * 4 + head];
        float eG = el[(size_t)sG * 4 + head];
        float eH = el[(size_t)sH * 4 + head];
        ushort4 uA = *(const ushort4*)(fbase + sA * hstr);
        ushort4 uB = *(const ushort4*)(fbase + sB * hstr);
        ushort4 uC = *(const ushort4*)(fbase + sC * hstr);
        ushort4 uD = *(const ushort4*)(fbase + sD * hstr);
        ushort4 uE = *(const ushort4*)(fbase + sE * hstr);
        ushort4 uF = *(const ushort4*)(fbase + sF * hstr);
        ushort4 uG = *(const ushort4*)(fbase + sG * hstr);
        ushort4 uH = *(const ushort4*)(fbase + sH * hstr);
        float wA = __expf(leaky(eA + erh));
        float wB = __expf(leaky(eB + erh));
        float wC = __expf(leaky(eC + erh));
        float wD = __expf(leaky(eD + erh));
        float wE = __expf(leaky(eE + erh));
        float wF = __expf(leaky(eF + erh));
        float wG = __expf(leaky(eG + erh));
        float wH = __expf(leaky(eH + erh));
        ssum += wA + wB + wC + wD + wE + wF + wG + wH;
        acc.x = fmaf(wA, bf2f(uA.x), acc.x); acc.y = fmaf(wA, bf2f(uA.y), acc.y);
        acc.z = fmaf(wA, bf2f(uA.z), acc.z); acc.w = fmaf(wA, bf2f(uA.w), acc.w);
        acc.x = fmaf(wB, bf2f(uB.x), acc.x); acc.y = fmaf(wB, bf2f(uB.y), acc.y);
        acc.z = fmaf(wB, bf2f(uB.z), acc.z); acc.w = fmaf(wB, bf2f(uB.w), acc.w);
        acc.x = fmaf(wC, bf2f(uC.x), acc.x); acc.y = fmaf(wC, bf2f(uC.y), acc.y);
        acc.z = fmaf(wC, bf2f(uC.z), acc.z); acc.w = fmaf(wC, bf2f(uC.w), acc.w);
        acc.x = fmaf(wD, bf2f(uD.x), acc.x); acc.y = fmaf(wD, bf2f(uD.y), acc.y);
        acc.z = fmaf(wD, bf2f(uD.z), acc.z); acc.w = fmaf(wD, bf2f(uD.w), acc.w);
        acc.x = fmaf(wE, bf2f(uE.x), acc.x); acc.y = fmaf(wE, bf2f(uE.y), acc.y);
        acc.z = fmaf(wE, bf2f(uE.z), acc.z); acc.w = fmaf(wE, bf2f(uE.w), acc.w);
        acc.x = fmaf(wF, bf2f(uF.x), acc.x); acc.y = fmaf(wF, bf2f(uF.y), acc.y);
        acc.z = fmaf(wF, bf2f(uF.z), acc.z); acc.w = fmaf(wF, bf2f(uF.w), acc.w);
        acc.x = fmaf(wG, bf2f(uG.x), acc.x); acc.y = fmaf(wG, bf2f(uG.y), acc.y);
        acc.z = fmaf(wG, bf2f(uG.z), acc.z); acc.w = fmaf(wG, bf2f(uG.w), acc.w);
        acc.x = fmaf(wH, bf2f(uH.x), acc.x); acc.y = fmaf(wH, bf2f(uH.y), acc.y);
        acc.z = fmaf(wH, bf2f(uH.z), acc.z); acc.w = fmaf(wH, bf2f(uH.w), acc.w);
    }
    for (; e < end; ++e) {
        int sA = col[e];
        float wA = __expf(leaky(el[(size_t)sA * 4 + head] + erh));
        ushort4 uA = *(const ushort4*)(fbase + sA * hstr);
        ssum += wA;
        acc.x = fmaf(wA, bf2f(uA.x), acc.x); acc.y = fmaf(wA, bf2f(uA.y), acc.y);
        acc.z = fmaf(wA, bf2f(uA.z), acc.z); acc.w = fmaf(wA, bf2f(uA.w), acc.w);
    }
    float inv = ssum > 0.f ? 1.f / ssum : 0.f;
    acc.x *= inv; acc.y *= inv; acc.z *= inv; acc.w *= inv;

    float4 bb = *(const float4*)(bias + ch);
    float x0 = acc.x + bb.x, x1 = acc.y + bb.y, x2 = acc.z + bb.z, x3 = acc.w + bb.w;
    x0 = x0 > 0.f ? x0 : expm1f(x0);
    x1 = x1 > 0.f ? x1 : expm1f(x1);
    x2 = x2 > 0.f ? x2 : expm1f(x2);
    x3 = x3 > 0.f ? x3 : expm1f(x3);
    float lsum = x0 + x1 + x2 + x3;
    float lsq = x0 * x0 + x1 * x1 + x2 * x2 + x3 * x3;
#pragma unroll
    for (int off = 32; off >= 1; off >>= 1) {
        lsum += __shfl_xor(lsum, off);
        lsq += __shfl_xor(lsq, off);
    }
    float mu = lsum * (1.f / 256.f);
    float var = lsq * (1.f / 256.f) - mu * mu;
    float rstd = rsqrtf(var + 1e-5f);
    float4 g4 = *(const float4*)(lng + ch);
    float4 b4 = *(const float4*)(lnb + ch);
    ushort4 hi = *(const ushort4*)(h_in + (size_t)node * 256 + ch);
    float y0 = (x0 - mu) * rstd * g4.x + b4.x;
    float y1 = (x1 - mu) * rstd * g4.y + b4.y;
    float y2 = (x2 - mu) * rstd * g4.z + b4.z;
    float y3 = (x3 - mu) * rstd * g4.w + b4.w;
    y0 = (y0 >= 0.f ? y0 : 0.2f * y0) + bf2f(hi.x);
    y1 = (y1 >= 0.f ? y1 : 0.2f * y1) + bf2f(hi.y);
    y2 = (y2 >= 0.f ? y2 : 0.2f * y2) + bf2f(hi.z);
    y3 = (y3 >= 0.f ? y3 : 0.2f * y3) + bf2f(hi.w);
    ushort4 o;
    o.x = f2bf(y0); o.y = f2bf(y1); o.z = f2bf(y2); o.w = f2bf(y3);
    *(ushort4*)(h_out + (size_t)node * 256 + ch) = o;
}

// ---------------- output aggregation: logits[N,40], single pass ----------------
__global__ __launch_bounds__(256) void aggregate_out(const unsigned short* __restrict__ feat_o,
                                                     const float* __restrict__ elo,
                                                     const float* __restrict__ ero,
                                                     const int* __restrict__ start,
                                                     const int* __restrict__ endp,
                                                     const int* __restrict__ col,
                                                     const float* __restrict__ bias_o,
                                                     float* __restrict__ out, int N) {
    int node = blockIdx.x * 4 + (threadIdx.x >> 6);
    int lane = threadIdx.x & 63;
    if (node >= N) return;
    int begin = __builtin_amdgcn_readfirstlane(start[node]);
    int end = __builtin_amdgcn_readfirstlane(endp[node]);
    float ern = ero[node];
    int cc = lane < 40 ? lane : 0;
    float acc = 0.f, ssum = 0.f;
    int e = begin;
    for (; e + 7 < end; e += 8) {
        int sA = col[e], sB = col[e + 1], sC = col[e + 2], sD = col[e + 3];
        int sE = col[e + 4], sF = col[e + 5], sG = col[e + 6], sH = col[e + 7];
        float eA = elo[sA], eB = elo[sB], eC = elo[sC], eD = elo[sD];
        float eE = elo[sE], eF = elo[sF], eG = elo[sG], eH = elo[sH];
        unsigned short fA = feat_o[(size_t)sA * 40 + cc];
        unsigned short fB = feat_o[(size_t)sB * 40 + cc];
        unsigned short fC = feat_o[(size_t)sC * 40 + cc];
        unsigned short fD = feat_o[(size_t)sD * 40 + cc];
        unsigned short fE = feat_o[(size_t)sE * 40 + cc];
        unsigned short fF = feat_o[(size_t)sF * 40 + cc];
        unsigned short fG = feat_o[(size_t)sG * 40 + cc];
        unsigned short fH = feat_o[(size_t)sH * 40 + cc];
        float wA = __expf(leaky(eA + ern));
        float wB = __expf(leaky(eB + ern));
        float wC = __expf(leaky(eC + ern));
        float wD = __expf(leaky(eD + ern));
        float wE = __expf(leaky(eE + ern));
        float wF = __expf(leaky(eF + ern));
        float wG = __expf(leaky(eG + ern));
        float wH = __expf(leaky(eH + ern));
        ssum += wA + wB + wC + wD + wE + wF + wG + wH;
        acc = fmaf(wA, bf2f(fA), acc);
        acc = fmaf(wB, bf2f(fB), acc);
        acc = fmaf(wC, bf2f(fC), acc);
        acc = fmaf(wD, bf2f(fD), acc);
        acc = fmaf(wE, bf2f(fE), acc);
        acc = fmaf(wF, bf2f(fF), acc);
        acc = fmaf(wG, bf2f(fG), acc);
        acc = fmaf(wH, bf2f(fH), acc);
    }
    for (; e < end; ++e) {
        int sA = col[e];
        float wA = __expf(leaky(elo[sA] + ern));
        ssum += wA;
        acc = fmaf(wA, bf2f(feat_o[(size_t)sA * 40 + cc]), acc);
    }
    float inv = ssum > 0.f ? 1.f / ssum : 0.f;
    if (lane < 40) out[(size_t)node * 40 + lane] = acc * inv + bias_o[lane];
}

// ---------------- launcher ----------------
extern "C" void kernel_launch(void* const* d_in, const int* in_sizes, int n_in,
                              void* d_out, int out_size, void* d_ws, size_t ws_size,
                              hipStream_t stream) {
    const float* x = (const float*)d_in[0];
    const float* W_h = (const float*)d_in[1];
    const float* al_h = (const float*)d_in[2];
    const float* ar_h = (const float*)d_in[3];
    const float* bias_h = (const float*)d_in[4];
    const float* ln_g = (const float*)d_in[5];
    const float* ln_b = (const float*)d_in[6];
    const float* W_o = (const float*)d_in[7];
    const float* al_o = (const float*)d_in[8];
    const float* ar_o = (const float*)d_in[9];
    const float* bias_o = (const float*)d_in[10];
    const int* esrc = (const int*)d_in[11];
    const int* edst = (const int*)d_in[12];
    const int N = in_sizes[0] / 256;
    const int E = in_sizes[11];
    float* out = (float*)d_out;

    char* ws = (char*)d_ws;
    size_t off = 0;
    auto walloc = [&](size_t bytes) -> void* {
        void* p = ws + off;
        off += (bytes + 255) & ~(size_t)255;
        return p;
    };
    unsigned short* x_bf = (unsigned short*)walloc((size_t)N * 256 * 2);
    unsigned short* h_bf = (unsigned short*)walloc((size_t)N * 256 * 2);
    unsigned short* feat_bf = (unsigned short*)walloc((size_t)N * 256 * 2);
    unsigned short* Wt = (unsigned short*)walloc((size_t)3 * 65536 * 2);
    unsigned short* Wt_o = (unsigned short*)walloc((size_t)48 * 256 * 2);
    float* el = (float*)walloc((size_t)N * 4 * 4);
    float* er = (float*)walloc((size_t)N * 4 * 4);
    int* counts = (int*)walloc(((size_t)N + 1) * 4);
    int* start = (int*)walloc((size_t)N * 4);
    int* endp = (int*)walloc((size_t)N * 4);
    int* col = (int*)walloc((size_t)E * 4);
    int* lscan = (int*)walloc((size_t)N * 4);
    int* bsum = (int*)walloc(128 * 4);
    if (off > ws_size) return;

    const int TB = 256;
    const int nbscan = (N + 1023) / 1024;
    convert_bf<<<(N * 64 + TB - 1) / TB, TB, 0, stream>>>(x, x_bf, N * 64);
    transpose_w<<<3 * 65536 / TB, TB, 0, stream>>>(W_h, Wt);
    transpose_wo<<<48, TB, 0, stream>>>(W_o, Wt_o);
    zero_i32<<<(N + TB - 1) / TB, TB, 0, stream>>>(counts, N);
    hist_kernel<<<(E + TB - 1) / TB, TB, 0, stream>>>(edst, counts, E);
    scan1<<<nbscan, TB, 0, stream>>>(counts, lscan, bsum, N);
    scan2<<<1, 128, 0, stream>>>(bsum, nbscan);
    scan3<<<(N + TB - 1) / TB, TB, 0, stream>>>(lscan, bsum, start, endp, N);
    scatter_kernel<<<(E + TB - 1) / TB, TB, 0, stream>>>(esrc, edst, endp, col, E);

    const int N2 = ((N / 2) + 3) & ~3;            // first-half node count, x4 aligned
    const int nbh1 = (N2 + 3) / 4;
    const int nbh2 = (N - N2 + 3) / 4;
    for (int l = 0; l < 3; ++l) {
        const unsigned short* hin = (l == 0) ? x_bf : h_bf;
        gemm_bf16_fused<<<256, 512, 0, stream>>>(hin, Wt + (size_t)l * 65536,
                                                 al_h + l * 256, ar_h + l * 256,
                                                 feat_bf, el, er, N);
        aggregate_hidden<<<nbh1, 256, 0, stream>>>(feat_bf, el, er, start, endp, col,
                                                   bias_h + l * 256, ln_g + l * 256,
                                                   ln_b + l * 256, hin, h_bf, 0, N2);
        aggregate_hidden<<<nbh2, 256, 0, stream>>>(feat_bf, el, er, start, endp, col,
                                                   bias_h + l * 256, ln_g + l * 256,
                                                   ln_b + l * 256, hin, h_bf, N2, N);
    }
    unsigned short* feat_o = feat_bf;
    float* elo = el;
    float* ero = er;
    gemm_out_mfma<<<(N + 127) / 128, 256, 0, stream>>>(h_bf, Wt_o, al_o, ar_o, feat_o, elo, ero, N);
    aggregate_out<<<(N + 3) / 4, 256, 0, stream>>>(feat_o, elo, ero, start, endp, col, bias_o, out, N);
}

// Round 5
// 905.587 us; speedup vs baseline: 1.1032x; 1.1032x over previous
//
#include <hip/hip_runtime.h>
#include <math.h>

// GAT: 3 hidden GATConv layers (H=4, D=64, HID=256) + LN + leaky + residual,
// then output GATConv (H=1, C=40). N=100000 nodes, E=1600000 edges.
//
// Round 14: CSR build rewritten as bucketed counting sort. R13 exposed
// scatter_kernel = 126 us with WRITE_SIZE 105 MB (= 1.6M x 64B line
// amplification: random 4B col stores from different XCDs). New build:
// (1) bucket_count: LDS hist over 782 buckets (dst>>7), (2) bucket_scan,
// (3) bucket_partition: per-block chunk reservation, grouped (src,dst)
// pair writes (block-exclusive chunks), (4) csr_bucket: one block OWNS
// each bucket's contiguous col range: LDS count+scan -> start/endp ->
// LDS-cursor scatter. Every col line written by one block. hist/scan123/
// scatter deleted. aggregate_out split in halves for visibility.

#define NEG_SLOPE 0.2f

typedef __attribute__((ext_vector_type(8))) short bf16x8;
typedef __attribute__((ext_vector_type(4))) float floatx4;

__device__ __forceinline__ float leaky(float x) { return x >= 0.f ? x : NEG_SLOPE * x; }

__device__ __forceinline__ unsigned short f2bf(float f) {
    unsigned u = __builtin_bit_cast(unsigned, f);
    u += 0x7fffu + ((u >> 16) & 1u);  // RNE
    return (unsigned short)(u >> 16);
}
__device__ __forceinline__ float bf2f(unsigned short h) {
    unsigned u = ((unsigned)h) << 16;
    return __builtin_bit_cast(float, u);
}

// ---------------- bucketed CSR build ----------------
// bucket = dst >> 7 (128 nodes/bucket); nbkt = ceil(N/128) <= 1024.
__global__ void zero_i32(int* __restrict__ p, int n) {
    int i = blockIdx.x * blockDim.x + threadIdx.x;
    if (i < n) p[i] = 0;
}

__global__ __launch_bounds__(256) void bucket_count(const int* __restrict__ dst,
                                                    int* __restrict__ bcnt, int E, int nbkt) {
    __shared__ int h[1024];
    for (int i = threadIdx.x; i < nbkt; i += 256) h[i] = 0;
    __syncthreads();
    const int base = blockIdx.x * 8192;
#pragma unroll 4
    for (int i = 0; i < 32; ++i) {
        int e = base + threadIdx.x + i * 256;
        if (e < E) atomicAdd(&h[dst[e] >> 7], 1);
    }
    __syncthreads();
    for (int i = threadIdx.x; i < nbkt; i += 256) {
        int v = h[i];
        if (v) atomicAdd(&bcnt[i], v);
    }
}

// single block: exclusive scan of nbkt (<=1024) bucket sizes
__global__ __launch_bounds__(256) void bucket_scan(const int* __restrict__ bcnt,
                                                   int* __restrict__ bbase,
                                                   int* __restrict__ bcursor, int nbkt) {
    __shared__ int s[256];
    const int t = threadIdx.x;
    int c[4];
    int tsum = 0;
#pragma unroll
    for (int j = 0; j < 4; ++j) {
        int i = t * 4 + j;
        c[j] = (i < nbkt) ? bcnt[i] : 0;
        tsum += c[j];
    }
    s[t] = tsum;
    __syncthreads();
    for (int off = 1; off < 256; off <<= 1) {
        int v = (t >= off) ? s[t - off] : 0;
        __syncthreads();
        s[t] += v;
        __syncthreads();
    }
    int excl = s[t] - tsum;
#pragma unroll
    for (int j = 0; j < 4; ++j) {
        int i = t * 4 + j;
        if (i < nbkt) {
            bbase[i] = excl;
            bcursor[i] = excl;
        }
        excl += c[j];
    }
}

// partition edges into bucket-grouped (src,dst) pairs; per-block chunk
// reservation -> block-exclusive write ranges (no cross-XCD line sharing)
__global__ __launch_bounds__(256) void bucket_partition(const int* __restrict__ src,
                                                        const int* __restrict__ dst,
                                                        int* __restrict__ bcursor,
                                                        int2* __restrict__ pairs, int E, int nbkt) {
    __shared__ int h[1024];
    __shared__ int basech[1024];
    for (int i = threadIdx.x; i < nbkt; i += 256) h[i] = 0;
    __syncthreads();
    const int base = blockIdx.x * 8192;
#pragma unroll 4
    for (int i = 0; i < 32; ++i) {
        int e = base + threadIdx.x + i * 256;
        if (e < E) atomicAdd(&h[dst[e] >> 7], 1);
    }
    __syncthreads();
    for (int i = threadIdx.x; i < nbkt; i += 256) {
        int v = h[i];
        basech[i] = v ? atomicAdd(&bcursor[i], v) : 0;
    }
    __syncthreads();
    for (int i = threadIdx.x; i < nbkt; i += 256) h[i] = 0;
    __syncthreads();
#pragma unroll 4
    for (int i = 0; i < 32; ++i) {
        int e = base + threadIdx.x + i * 256;
        if (e < E) {
            int d = dst[e], b = d >> 7;
            int r = atomicAdd(&h[b], 1);
            pairs[basech[b] + r] = make_int2(src[e], d);
        }
    }
}

// one block per bucket: local CSR (start/endp for its 128 nodes) + col
// scatter into the bucket's exclusive contiguous range.
__global__ __launch_bounds__(256) void csr_bucket(const int2* __restrict__ pairs,
                                                  const int* __restrict__ bbase,
                                                  int* __restrict__ start, int* __restrict__ endp,
                                                  int* __restrict__ col, int N, int E, int nbkt) {
    const int b = blockIdx.x;
    const int node0 = b << 7;
    int nc = N - node0;
    if (nc <= 0) return;
    if (nc > 128) nc = 128;
    __shared__ int cnt[128];
    __shared__ int s[128];
    const int t = threadIdx.x;
    if (t < 128) cnt[t] = 0;
    __syncthreads();
    const int ebase = bbase[b];
    const int eend = (b + 1 < nbkt) ? bbase[b + 1] : E;
    for (int e = ebase + t; e < eend; e += 256) {
        atomicAdd(&cnt[pairs[e].y - node0], 1);
    }
    __syncthreads();
    if (t < 128) s[t] = cnt[t];
    __syncthreads();
    for (int off = 1; off < 128; off <<= 1) {
        int v = 0;
        if (t < 128 && t >= off) v = s[t - off];
        __syncthreads();
        if (t < 128) s[t] += v;
        __syncthreads();
    }
    if (t < nc) {
        start[node0 + t] = ebase + s[t] - cnt[t];
        endp[node0 + t] = ebase + s[t];
    }
    if (t < 128) cnt[t] = s[t] - cnt[t];  // -> exclusive cursor
    __syncthreads();
    for (int e = ebase + t; e < eend; e += 256) {
        int2 pr = pairs[e];
        int r = atomicAdd(&cnt[pr.y - node0], 1);
        col[ebase + r] = pr.x;
    }
}

// ---------------- fp32 -> bf16 bulk convert ----------------
__global__ void convert_bf(const float* __restrict__ src, unsigned short* __restrict__ dst,
                           int n4) {
    int i = blockIdx.x * blockDim.x + threadIdx.x;
    if (i < n4) {
        float4 v = *(const float4*)(src + (size_t)i * 4);
        ushort4 s;
        s.x = f2bf(v.x); s.y = f2bf(v.y); s.z = f2bf(v.z); s.w = f2bf(v.w);
        *(ushort4*)(dst + (size_t)i * 4) = s;
    }
}

// ---------------- weight pre-transpose: Wt[l][n][k] = bf16(W[l][k][n]) ----------------
__global__ void transpose_w(const float* __restrict__ W, unsigned short* __restrict__ Wt) {
    int idx = blockIdx.x * 256 + threadIdx.x;
    int l = idx >> 16, r = idx & 65535;
    int k = r >> 8, n = r & 255;
    Wt[l * 65536 + n * 256 + k] = f2bf(W[l * 65536 + k * 256 + n]);
}

__global__ void transpose_wo(const float* __restrict__ W, unsigned short* __restrict__ Wt) {
    int idx = blockIdx.x * 256 + threadIdx.x;
    int n = idx >> 8, k = idx & 255;
    Wt[n * 256 + k] = (n < 40) ? f2bf(W[k * 40 + n]) : (unsigned short)0;
}

// ---------------- weight-resident persistent MFMA GEMM + fused scores ----------------
#define BPAD 264
#define ALD 40
__global__ __launch_bounds__(512, 2) void gemm_bf16_fused(
    const unsigned short* __restrict__ A, const unsigned short* __restrict__ Wt,
    const float* __restrict__ al, const float* __restrict__ ar,
    unsigned short* __restrict__ Cb, float* __restrict__ el, float* __restrict__ er, int M) {
    __shared__ unsigned short Bs[256 * BPAD];   // 132 KB
    __shared__ unsigned short As[2][128 * ALD]; // 20.5 KB
    const int tid = threadIdx.x;
    const int lane = tid & 63, wid = tid >> 6;
    const int wm = (wid >> 2) * 64;   // 0 or 64
    const int wn = (wid & 3) * 64;    // 0,64,128,192
    const int q = lane >> 4, m = lane & 15;

#pragma unroll
    for (int i = 0; i < 16; ++i) {
        int flat = tid + 512 * i;            // 16B units
        int row = flat >> 5, col8 = (flat & 31) * 8;
        *(bf16x8*)&Bs[row * BPAD + col8] = *(const bf16x8*)(Wt + row * 256 + col8);
    }
    __syncthreads();

    const int rA = tid >> 2, k8 = (tid & 3) * 8;
    const int head = wid & 3;
    const float* alh = al + head * 64;
    const float* arh = ar + head * 64;
    const int c = lane & 15;
    float a0 = alh[c], a1 = alh[16 + c], a2 = alh[32 + c], a3 = alh[48 + c];
    float r0 = arh[c], r1 = arh[16 + c], r2 = arh[32 + c], r3 = arh[48 + c];

    const int ntiles = (M + 127) >> 7;
    for (int t = blockIdx.x; t < ntiles; t += gridDim.x) {
        const int row0 = t << 7;
        int agr = row0 + rA; if (agr >= M) agr = M - 1;
        const unsigned short* arow = A + (size_t)agr * 256 + k8;
        bf16x8 pa = *(const bf16x8*)arow;

        floatx4 acc[4][4] = {};
        int cur = 0;
        for (int kb = 0; kb < 256; kb += 32) {
            *(bf16x8*)&As[cur][rA * ALD + k8] = pa;
            __syncthreads();
            if (kb + 32 < 256) pa = *(const bf16x8*)(arow + kb + 32);
            bf16x8 af[4], bfr[4];
#pragma unroll
            for (int i = 0; i < 4; ++i) {
                af[i] = *(const bf16x8*)&As[cur][(wm + i * 16 + m) * ALD + q * 8];
                bfr[i] = *(const bf16x8*)&Bs[(wn + i * 16 + m) * BPAD + kb + q * 8];
            }
#pragma unroll
            for (int i = 0; i < 4; ++i)
#pragma unroll
                for (int j = 0; j < 4; ++j)
                    acc[i][j] = __builtin_amdgcn_mfma_f32_16x16x32_bf16(af[i], bfr[j], acc[i][j], 0, 0, 0);
            cur ^= 1;
        }

#pragma unroll
        for (int i = 0; i < 4; ++i)
#pragma unroll
            for (int j = 0; j < 4; ++j)
#pragma unroll
                for (int r = 0; r < 4; ++r) {
                    int grow = row0 + wm + i * 16 + q * 4 + r;
                    int gcol = wn + j * 16 + c;
                    if (grow < M) Cb[(size_t)grow * 256 + gcol] = f2bf(acc[i][j][r]);
                }

#pragma unroll
        for (int i = 0; i < 4; ++i)
#pragma unroll
            for (int r = 0; r < 4; ++r) {
                float pel = acc[i][0][r] * a0 + acc[i][1][r] * a1 + acc[i][2][r] * a2 + acc[i][3][r] * a3;
                float per = acc[i][0][r] * r0 + acc[i][1][r] * r1 + acc[i][2][r] * r2 + acc[i][3][r] * r3;
#pragma unroll
                for (int off = 8; off >= 1; off >>= 1) {
                    pel += __shfl_xor(pel, off);
                    per += __shfl_xor(per, off);
                }
                if (c == 0) {
                    int grow = row0 + wm + i * 16 + q * 4 + r;
                    if (grow < M) {
                        el[(size_t)grow * 4 + head] = pel;
                        er[(size_t)grow * 4 + head] = per;
                    }
                }
            }
        __syncthreads();
    }
}

// ---------------- output MFMA GEMM: feat_o[N,40] bf16 = h_bf[N,256] @ W_o ----------------
#define LDSK 40
#define BSTRIDE 264
__global__ __launch_bounds__(256) void gemm_out_mfma(const unsigned short* __restrict__ h,
                                                     const unsigned short* __restrict__ Wt,
                                                     const float* __restrict__ alo,
                                                     const float* __restrict__ aro,
                                                     unsigned short* __restrict__ feat_o,
                                                     float* __restrict__ elo,
                                                     float* __restrict__ ero, int N) {
    __shared__ unsigned short As[128 * LDSK];
    __shared__ unsigned short Bs[48 * BSTRIDE];
    const int tid = threadIdx.x;
    const int row0 = blockIdx.x * 128;
    const int lane = tid & 63, wid = tid >> 6;

#pragma unroll
    for (int i = 0; i < 6; ++i) {
        int f = tid + 256 * i;
        int n = f >> 5, kk = (f & 31) * 8;
        *(bf16x8*)&Bs[n * BSTRIDE + kk] = *(const bf16x8*)(Wt + n * 256 + kk);
    }
    __syncthreads();

    floatx4 acc[2][3] = {};
    for (int kb = 0; kb < 256; kb += 32) {
#pragma unroll
        for (int i = 0; i < 2; ++i) {
            int idx = tid + 256 * i;
            int r = idx >> 2, k8 = (idx & 3) * 8;
            int gr = row0 + r;
            bf16x8 v = {};
            if (gr < N) v = *(const bf16x8*)(h + (size_t)gr * 256 + kb + k8);
            *(bf16x8*)&As[r * LDSK + k8] = v;
        }
        __syncthreads();
        const int q = lane >> 4, m = lane & 15;
        bf16x8 af[2], bfr[3];
#pragma unroll
        for (int i = 0; i < 2; ++i)
            af[i] = *(const bf16x8*)&As[(wid * 32 + i * 16 + m) * LDSK + q * 8];
#pragma unroll
        for (int j = 0; j < 3; ++j)
            bfr[j] = *(const bf16x8*)&Bs[(j * 16 + m) * BSTRIDE + kb + q * 8];
#pragma unroll
        for (int i = 0; i < 2; ++i)
#pragma unroll
            for (int j = 0; j < 3; ++j)
                acc[i][j] = __builtin_amdgcn_mfma_f32_16x16x32_bf16(af[i], bfr[j], acc[i][j], 0, 0, 0);
        __syncthreads();
    }

    const int q = lane >> 4, c = lane & 15;
#pragma unroll
    for (int i = 0; i < 2; ++i)
#pragma unroll
        for (int j = 0; j < 3; ++j)
#pragma unroll
            for (int r = 0; r < 4; ++r) {
                int grow = row0 + wid * 32 + i * 16 + q * 4 + r;
                int gcol = j * 16 + c;
                if (grow < N && gcol < 40) feat_o[(size_t)grow * 40 + gcol] = f2bf(acc[i][j][r]);
            }

    float aj[3], rj[3];
#pragma unroll
    for (int j = 0; j < 3; ++j) {
        int gcol = j * 16 + c;
        aj[j] = gcol < 40 ? alo[gcol] : 0.f;
        rj[j] = gcol < 40 ? aro[gcol] : 0.f;
    }
#pragma unroll
    for (int i = 0; i < 2; ++i)
#pragma unroll
        for (int r = 0; r < 4; ++r) {
            float pl = acc[i][0][r] * aj[0] + acc[i][1][r] * aj[1] + acc[i][2][r] * aj[2];
            float pr = acc[i][0][r] * rj[0] + acc[i][1][r] * rj[1] + acc[i][2][r] * rj[2];
#pragma unroll
            for (int off = 8; off >= 1; off >>= 1) {
                pl += __shfl_xor(pl, off);
                pr += __shfl_xor(pr, off);
            }
            if (c == 0) {
                int grow = row0 + wid * 32 + i * 16 + q * 4 + r;
                if (grow < N) {
                    elo[grow] = pl;
                    ero[grow] = pr;
                }
            }
        }
}

// ---------------- hidden-layer aggregation: single pass + fused epilogue ----------------
__global__ __launch_bounds__(256) void aggregate_hidden(
    const unsigned short* __restrict__ feat, const float* __restrict__ el,
    const float* __restrict__ er, const int* __restrict__ start, const int* __restrict__ endp,
    const int* __restrict__ col, const float* __restrict__ bias, const float* __restrict__ lng,
    const float* __restrict__ lnb, const unsigned short* __restrict__ h_in,
    unsigned short* __restrict__ h_out, int node0, int nend) {
    int node = node0 + blockIdx.x * 4 + (threadIdx.x >> 6);
    int lane = threadIdx.x & 63;
    if (node >= nend) return;
    int begin = __builtin_amdgcn_readfirstlane(start[node]);
    int end = __builtin_amdgcn_readfirstlane(endp[node]);
    const int head = lane >> 4;
    const float erh = er[(size_t)node * 4 + head];

    const int ch = lane * 4;
    const unsigned short* fbase = feat + ch;
    const size_t hstr = 256;
    float4 acc = {0.f, 0.f, 0.f, 0.f};
    float ssum = 0.f;
    int e = begin;
    for (; e + 7 < end; e += 8) {
        int sA = col[e], sB = col[e + 1], sC = col[e + 2], sD = col[e + 3];
        int sE = col[e + 4], sF = col[e + 5], sG = col[e + 6], sH = col[e + 7];
        float eA = el[(size_t)sA * 4 + head];
        float eB = el[(size_t)sB * 4 + head];
        float eC = el[(size_t)sC * 4 + head];
        float eD = el[(size_t)sD * 4 + head];
        float eE = el[(size_t)sE * 4 + head];
        float eF = el[(size_t)sF * 4 + head];
        float eG = el[(size_t)sG * 4 + head];
        float eH = el[(size_t)sH * 4 + head];
        ushort4 uA = *(const ushort4*)(fbase + sA * hstr);
        ushort4 uB = *(const ushort4*)(fbase + sB * hstr);
        ushort4 uC = *(const ushort4*)(fbase + sC * hstr);
        ushort4 uD = *(const ushort4*)(fbase + sD * hstr);
        ushort4 uE = *(const ushort4*)(fbase + sE * hstr);
        ushort4 uF = *(const ushort4*)(fbase + sF * hstr);
        ushort4 uG = *(const ushort4*)(fbase + sG * hstr);
        ushort4 uH = *(const ushort4*)(fbase + sH * hstr);
        float wA = __expf(leaky(eA + erh));
        float wB = __expf(leaky(eB + erh));
        float wC = __expf(leaky(eC + erh));
        float wD = __expf(leaky(eD + erh));
        float wE = __expf(leaky(eE + erh));
        float wF = __expf(leaky(eF + erh));
        float wG = __expf(leaky(eG + erh));
        float wH = __expf(leaky(eH + erh));
        ssum += wA + wB + wC + wD + wE + wF + wG + wH;
        acc.x = fmaf(wA, bf2f(uA.x), acc.x); acc.y = fmaf(wA, bf2f(uA.y), acc.y);
        acc.z = fmaf(wA, bf2f(uA.z), acc.z); acc.w = fmaf(wA, bf2f(uA.w), acc.w);
        acc.x = fmaf(wB, bf2f(uB.x), acc.x); acc.y = fmaf(wB, bf2f(uB.y), acc.y);
        acc.z = fmaf(wB, bf2f(uB.z), acc.z); acc.w = fmaf(wB, bf2f(uB.w), acc.w);
        acc.x = fmaf(wC, bf2f(uC.x), acc.x); acc.y = fmaf(wC, bf2f(uC.y), acc.y);
        acc.z = fmaf(wC, bf2f(uC.z), acc.z); acc.w = fmaf(wC, bf2f(uC.w), acc.w);
        acc.x = fmaf(wD, bf2f(uD.x), acc.x); acc.y = fmaf(wD, bf2f(uD.y), acc.y);
        acc.z = fmaf(wD, bf2f(uD.z), acc.z); acc.w = fmaf(wD, bf2f(uD.w), acc.w);
        acc.x = fmaf(wE, bf2f(uE.x), acc.x); acc.y = fmaf(wE, bf2f(uE.y), acc.y);
        acc.z = fmaf(wE, bf2f(uE.z), acc.z); acc.w = fmaf(wE, bf2f(uE.w), acc.w);
        acc.x = fmaf(wF, bf2f(uF.x), acc.x); acc.y = fmaf(wF, bf2f(uF.y), acc.y);
        acc.z = fmaf(wF, bf2f(uF.z), acc.z); acc.w = fmaf(wF, bf2f(uF.w), acc.w);
        acc.x = fmaf(wG, bf2f(uG.x), acc.x); acc.y = fmaf(wG, bf2f(uG.y), acc.y);
        acc.z = fmaf(wG, bf2f(uG.z), acc.z); acc.w = fmaf(wG, bf2f(uG.w), acc.w);
        acc.x = fmaf(wH, bf2f(uH.x), acc.x); acc.y = fmaf(wH, bf2f(uH.y), acc.y);
        acc.z = fmaf(wH, bf2f(uH.z), acc.z); acc.w = fmaf(wH, bf2f(uH.w), acc.w);
    }
    for (; e < end; ++e) {
        int sA = col[e];
        float wA = __expf(leaky(el[(size_t)sA * 4 + head] + erh));
        ushort4 uA = *(const ushort4*)(fbase + sA * hstr);
        ssum += wA;
        acc.x = fmaf(wA, bf2f(uA.x), acc.x); acc.y = fmaf(wA, bf2f(uA.y), acc.y);
        acc.z = fmaf(wA, bf2f(uA.z), acc.z); acc.w = fmaf(wA, bf2f(uA.w), acc.w);
    }
    float inv = ssum > 0.f ? 1.f / ssum : 0.f;
    acc.x *= inv; acc.y *= inv; acc.z *= inv; acc.w *= inv;

    float4 bb = *(const float4*)(bias + ch);
    float x0 = acc.x + bb.x, x1 = acc.y + bb.y, x2 = acc.z + bb.z, x3 = acc.w + bb.w;
    x0 = x0 > 0.f ? x0 : expm1f(x0);
    x1 = x1 > 0.f ? x1 : expm1f(x1);
    x2 = x2 > 0.f ? x2 : expm1f(x2);
    x3 = x3 > 0.f ? x3 : expm1f(x3);
    float lsum = x0 + x1 + x2 + x3;
    float lsq = x0 * x0 + x1 * x1 + x2 * x2 + x3 * x3;
#pragma unroll
    for (int off = 32; off >= 1; off >>= 1) {
        lsum += __shfl_xor(lsum, off);
        lsq += __shfl_xor(lsq, off);
    }
    float mu = lsum * (1.f / 256.f);
    float var = lsq * (1.f / 256.f) - mu * mu;
    float rstd = rsqrtf(var + 1e-5f);
    float4 g4 = *(const float4*)(lng + ch);
    float4 b4 = *(const float4*)(lnb + ch);
    ushort4 hi = *(const ushort4*)(h_in + (size_t)node * 256 + ch);
    float y0 = (x0 - mu) * rstd * g4.x + b4.x;
    float y1 = (x1 - mu) * rstd * g4.y + b4.y;
    float y2 = (x2 - mu) * rstd * g4.z + b4.z;
    float y3 = (x3 - mu) * rstd * g4.w + b4.w;
    y0 = (y0 >= 0.f ? y0 : 0.2f * y0) + bf2f(hi.x);
    y1 = (y1 >= 0.f ? y1 : 0.2f * y1) + bf2f(hi.y);
    y2 = (y2 >= 0.f ? y2 : 0.2f * y2) + bf2f(hi.z);
    y3 = (y3 >= 0.f ? y3 : 0.2f * y3) + bf2f(hi.w);
    ushort4 o;
    o.x = f2bf(y0); o.y = f2bf(y1); o.z = f2bf(y2); o.w = f2bf(y3);
    *(ushort4*)(h_out + (size_t)node * 256 + ch) = o;
}

// ---------------- output aggregation: logits[N,40], single pass ----------------
__global__ __launch_bounds__(256) void aggregate_out(const unsigned short* __restrict__ feat_o,
                                                     const float* __restrict__ elo,
                                                     const float* __restrict__ ero,
                                                     const int* __restrict__ start,
                                                     const int* __restrict__ endp,
                                                     const int* __restrict__ col,
                                                     const float* __restrict__ bias_o,
                                                     float* __restrict__ out, int node0, int nend) {
    int node = node0 + blockIdx.x * 4 + (threadIdx.x >> 6);
    int lane = threadIdx.x & 63;
    if (node >= nend) return;
    int begin = __builtin_amdgcn_readfirstlane(start[node]);
    int end = __builtin_amdgcn_readfirstlane(endp[node]);
    float ern = ero[node];
    int cc = lane < 40 ? lane : 0;
    float acc = 0.f, ssum = 0.f;
    int e = begin;
    for (; e + 7 < end; e += 8) {
        int sA = col[e], sB = col[e + 1], sC = col[e + 2], sD = col[e + 3];
        int sE = col[e + 4], sF = col[e + 5], sG = col[e + 6], sH = col[e + 7];
        float eA = elo[sA], eB = elo[sB], eC = elo[sC], eD = elo[sD];
        float eE = elo[sE], eF = elo[sF], eG = elo[sG], eH = elo[sH];
        unsigned short fA = feat_o[(size_t)sA * 40 + cc];
        unsigned short fB = feat_o[(size_t)sB * 40 + cc];
        unsigned short fC = feat_o[(size_t)sC * 40 + cc];
        unsigned short fD = feat_o[(size_t)sD * 40 + cc];
        unsigned short fE = feat_o[(size_t)sE * 40 + cc];
        unsigned short fF = feat_o[(size_t)sF * 40 + cc];
        unsigned short fG = feat_o[(size_t)sG * 40 + cc];
        unsigned short fH = feat_o[(size_t)sH * 40 + cc];
        float wA = __expf(leaky(eA + ern));
        float wB = __expf(leaky(eB + ern));
        float wC = __expf(leaky(eC + ern));
        float wD = __expf(leaky(eD + ern));
        float wE = __expf(leaky(eE + ern));
        float wF = __expf(leaky(eF + ern));
        float wG = __expf(leaky(eG + ern));
        float wH = __expf(leaky(eH + ern));
        ssum += wA + wB + wC + wD + wE + wF + wG + wH;
        acc = fmaf(wA, bf2f(fA), acc);
        acc = fmaf(wB, bf2f(fB), acc);
        acc = fmaf(wC, bf2f(fC), acc);
        acc = fmaf(wD, bf2f(fD), acc);
        acc = fmaf(wE, bf2f(fE), acc);
        acc = fmaf(wF, bf2f(fF), acc);
        acc = fmaf(wG, bf2f(fG), acc);
        acc = fmaf(wH, bf2f(fH), acc);
    }
    for (; e < end; ++e) {
        int sA = col[e];
        float wA = __expf(leaky(elo[sA] + ern));
        ssum += wA;
        acc = fmaf(wA, bf2f(feat_o[(size_t)sA * 40 + cc]), acc);
    }
    float inv = ssum > 0.f ? 1.f / ssum : 0.f;
    if (lane < 40) out[(size_t)node * 40 + lane] = acc * inv + bias_o[lane];
}

// ---------------- launcher ----------------
extern "C" void kernel_launch(void* const* d_in, const int* in_sizes, int n_in,
                              void* d_out, int out_size, void* d_ws, size_t ws_size,
                              hipStream_t stream) {
    const float* x = (const float*)d_in[0];
    const float* W_h = (const float*)d_in[1];
    const float* al_h = (const float*)d_in[2];
    const float* ar_h = (const float*)d_in[3];
    const float* bias_h = (const float*)d_in[4];
    const float* ln_g = (const float*)d_in[5];
    const float* ln_b = (const float*)d_in[6];
    const float* W_o = (const float*)d_in[7];
    const float* al_o = (const float*)d_in[8];
    const float* ar_o = (const float*)d_in[9];
    const float* bias_o = (const float*)d_in[10];
    const int* esrc = (const int*)d_in[11];
    const int* edst = (const int*)d_in[12];
    const int N = in_sizes[0] / 256;
    const int E = in_sizes[11];
    float* out = (float*)d_out;

    char* ws = (char*)d_ws;
    size_t off = 0;
    auto walloc = [&](size_t bytes) -> void* {
        void* p = ws + off;
        off += (bytes + 255) & ~(size_t)255;
        return p;
    };
    unsigned short* x_bf = (unsigned short*)walloc((size_t)N * 256 * 2);
    unsigned short* h_bf = (unsigned short*)walloc((size_t)N * 256 * 2);
    unsigned short* feat_bf = (unsigned short*)walloc((size_t)N * 256 * 2);
    unsigned short* Wt = (unsigned short*)walloc((size_t)3 * 65536 * 2);
    unsigned short* Wt_o = (unsigned short*)walloc((size_t)48 * 256 * 2);
    float* el = (float*)walloc((size_t)N * 4 * 4);
    float* er = (float*)walloc((size_t)N * 4 * 4);
    int* start = (int*)walloc((size_t)N * 4);
    int* endp = (int*)walloc((size_t)N * 4);
    int* col = (int*)walloc((size_t)E * 4);
    int* bcnt = (int*)walloc(1024 * 4);
    int* bbase = (int*)walloc(1024 * 4);
    int* bcursor = (int*)walloc(1024 * 4);
    int2* pairs = (int2*)walloc((size_t)E * 8);
    if (off > ws_size) return;

    const int TB = 256;
    const int nbkt = (N + 127) >> 7;            // 128 nodes per bucket
    const int nbe = (E + 8191) / 8192;
    convert_bf<<<(N * 64 + TB - 1) / TB, TB, 0, stream>>>(x, x_bf, N * 64);
    transpose_w<<<3 * 65536 / TB, TB, 0, stream>>>(W_h, Wt);
    transpose_wo<<<48, TB, 0, stream>>>(W_o, Wt_o);
    zero_i32<<<(nbkt + TB - 1) / TB, TB, 0, stream>>>(bcnt, nbkt);
    bucket_count<<<nbe, TB, 0, stream>>>(edst, bcnt, E, nbkt);
    bucket_scan<<<1, TB, 0, stream>>>(bcnt, bbase, bcursor, nbkt);
    bucket_partition<<<nbe, TB, 0, stream>>>(esrc, edst, bcursor, pairs, E, nbkt);
    csr_bucket<<<nbkt, TB, 0, stream>>>(pairs, bbase, start, endp, col, N, E, nbkt);

    const int N2 = ((N / 2) + 3) & ~3;            // first-half node count, x4 aligned
    const int nbh1 = (N2 + 3) / 4;
    const int nbh2 = (N - N2 + 3) / 4;
    for (int l = 0; l < 3; ++l) {
        const unsigned short* hin = (l == 0) ? x_bf : h_bf;
        gemm_bf16_fused<<<256, 512, 0, stream>>>(hin, Wt + (size_t)l * 65536,
                                                 al_h + l * 256, ar_h + l * 256,
                                                 feat_bf, el, er, N);
        aggregate_hidden<<<nbh1, 256, 0, stream>>>(feat_bf, el, er, start, endp, col,
                                                   bias_h + l * 256, ln_g + l * 256,
                                                   ln_b + l * 256, hin, h_bf, 0, N2);
        aggregate_hidden<<<nbh2, 256, 0, stream>>>(feat_bf, el, er, start, endp, col,
                                                   bias_h + l * 256, ln_g + l * 256,
                                                   ln_b + l * 256, hin, h_bf, N2, N);
    }
    unsigned short* feat_o = feat_bf;
    float* elo = el;
    float* ero = er;
    gemm_out_mfma<<<(N + 127) / 128, 256, 0, stream>>>(h_bf, Wt_o, al_o, ar_o, feat_o, elo, ero, N);
    aggregate_out<<<nbh1, 256, 0, stream>>>(feat_o, elo, ero, start, endp, col, bias_o, out, 0, N2);
    aggregate_out<<<nbh2, 256, 0, stream>>>(feat_o, elo, ero, start, endp, col, bias_o, out, N2, N);
}